// Round 1
// 138.197 us; speedup vs baseline: 1.1207x; 1.1207x over previous
//
#include <hip/hip_runtime.h>

// Conv2D 15x15 valid, 4096^2 fp32 -> 4082^2 fp32, via bf16 MFMA Toeplitz-band.
//
// Per kh: C[16x16] += A(16x32) * B(32x16) with A = x rows (bf16 LDS tile),
// B[k][n] = w[kh][k-n] band (0 outside). Memory-bound floor ~22 us (134 MB).
//
// R1 changes vs 72us/dispatch baseline (latency-bound: MFMA 8.5%, VALU 24%,
// HBM 21%, occ 45%):
//  - B-frag table built ONCE by prep kernel into d_ws (was rebuilt per block:
//    ~120 wave-VMEM + ~1.5k VALU cyc per block, pure waste). Main kernel
//    loads B[kh] as coalesced 16B/lane global loads (15 KB table, L1-hot).
//  - LDS drops 29184 -> 13728 B; __launch_bounds__(256,8) -> 8 blocks/CU
//    (32 waves) vs 5 blocks (20 waves).
//  - Interior blocks (63x63 of 64x64) stage via branch-free unrolled batch:
//    all 7 float4 loads issued before converts (was: per-item branchy loop,
//    one ~900cy HBM load at a time).

#define HIN 4096
#define WIN 4096
#define KH 15
#define KW 15
#define OH (HIN - KH + 1)  // 4082
#define OW (WIN - KW + 1)  // 4082

#define BX 64
#define BY 64
#define XROWS (BY + KH - 1)     // 78 staged input rows
#define XCOLS 80                // staged input cols (64 + 14, padded to 80)
#define LDSW 88                 // bf16 row stride (176 B -> bank skew 12 dwords)
#define NSH (XROWS * LDSW)      // 6864 shorts = 13728 B LDS
#define NB4 (XCOLS / 4)         // 20 float4 per staged row
#define NITEM (XROWS * NB4)     // 1560 staging items per block

typedef short bf16x8 __attribute__((ext_vector_type(8)));
typedef float f32x4  __attribute__((ext_vector_type(4)));

static __device__ inline short f2bf(float f) {  // fp32 -> bf16 RNE
    unsigned u = __float_as_uint(f);
    u += 0x7fffu + ((u >> 16) & 1u);
    return (short)(u >> 16);
}

// ---- prep: build B-fragment table (15 kh x 64 lanes x bf16x8) once in ws ----
// Fragment layout for mfma_16x16x32 B-operand: lane L holds
// B[k=(L>>4)*8+j][n=L&15], j=0..7, with B[k][n] = w[kh][k-n] (0 outside band).
__global__ void conv2d_btab(const float* __restrict__ w, short* __restrict__ btab) {
    const int e = blockIdx.x * 256 + threadIdx.x;
    if (e >= KH * 64) return;
    const int kh = e >> 6;
    const int L  = e & 63;
    const int n  = L & 15;
    const int q  = L >> 4;
    bf16x8 bv;
#pragma unroll
    for (int j = 0; j < 8; ++j) {
        const int d = q * 8 + j - n;          // k - n
        bv[j] = (d >= 0 && d < KW) ? f2bf(w[kh * KW + d]) : (short)0;
    }
    *reinterpret_cast<bf16x8*>(&btab[(size_t)e * 8]) = bv;
}

__global__ __launch_bounds__(256, 8)
void conv2d_mfma(const float* __restrict__ x,
                 const short* __restrict__ btab,
                 const float* __restrict__ bias,
                 float* __restrict__ out) {
    __shared__ short lds[NSH];

    const int tid = threadIdx.x;
    const int ox0 = blockIdx.x * BX;
    const int oy0 = blockIdx.y * BY;

    // ---------------- stage x tile: 78 x 80 fp32 -> bf16 LDS ----------------
    if (ox0 + XCOLS <= WIN && oy0 + XROWS <= HIN) {
        // interior fast path: no clamps; batch-issue all loads, then convert
        float4 v[7];
#pragma unroll
        for (int i = 0; i < 7; ++i) {
            const int f = tid + 256 * i;
            if (f < NITEM) {
                const int r  = f / NB4;
                const int c4 = (f - r * NB4) * 4;
                v[i] = *reinterpret_cast<const float4*>(&x[(size_t)(oy0 + r) * WIN + ox0 + c4]);
            }
        }
#pragma unroll
        for (int i = 0; i < 7; ++i) {
            const int f = tid + 256 * i;
            if (f < NITEM) {
                const int r  = f / NB4;
                const int c4 = (f - r * NB4) * 4;
                short4 s;
                s.x = f2bf(v[i].x); s.y = f2bf(v[i].y);
                s.z = f2bf(v[i].z); s.w = f2bf(v[i].w);
                *reinterpret_cast<short4*>(&lds[r * LDSW + c4]) = s;   // ds_write_b64
            }
        }
    } else {
        // edge blocks (bx==63 or by==63): clamped per-item path
        for (int f = tid; f < NITEM; f += 256) {
            const int r  = f / NB4;
            const int c4 = (f - r * NB4) * 4;
            int gy = oy0 + r;
            if (gy > HIN - 1) gy = HIN - 1;   // clamped rows feed only masked outputs
            const int gx = ox0 + c4;
            float4 v;
            if (gx + 3 <= WIN - 1) {
                v = *reinterpret_cast<const float4*>(&x[(size_t)gy * WIN + gx]);
            } else {
                const float* row = &x[(size_t)gy * WIN];
                const int x0 = (gx + 0 > WIN - 1) ? WIN - 1 : gx + 0;
                const int x1 = (gx + 1 > WIN - 1) ? WIN - 1 : gx + 1;
                const int x2 = (gx + 2 > WIN - 1) ? WIN - 1 : gx + 2;
                const int x3 = (gx + 3 > WIN - 1) ? WIN - 1 : gx + 3;
                v = make_float4(row[x0], row[x1], row[x2], row[x3]);
            }
            short4 s;
            s.x = f2bf(v.x); s.y = f2bf(v.y); s.z = f2bf(v.z); s.w = f2bf(v.w);
            *reinterpret_cast<short4*>(&lds[r * LDSW + c4]) = s;
        }
    }
    __syncthreads();

    // ---------------- compute: 15 kh x 4 x-tiles of 16x16 MFMA ----------------
    const int lane = tid & 63;
    const int wv   = tid >> 6;        // wave id 0..3 -> output rows [16*wv, +16)
    const int m    = lane & 15;       // A-row (and D-col) index
    const int q    = lane >> 4;       // quad

    f32x4 acc[4];
#pragma unroll
    for (int t = 0; t < 4; ++t) acc[t] = (f32x4){0.f, 0.f, 0.f, 0.f};

    // A-frag base: row (16*wv + m + kh), col q*8 + t*16 (imm-friendly offsets)
    const short*  abase = &lds[(wv * 16 + m) * LDSW + q * 8];
    const bf16x8* bt    = reinterpret_cast<const bf16x8*>(btab) + lane;
#pragma unroll
    for (int kh = 0; kh < KH; ++kh) {
        const bf16x8 b = bt[kh * 64];   // global_load_dwordx4, L1-hot (15 KB table)
#pragma unroll
        for (int t = 0; t < 4; ++t) {
            const bf16x8 a =
                *reinterpret_cast<const bf16x8*>(abase + kh * LDSW + t * 16);  // ds_read_b128
            acc[t] = __builtin_amdgcn_mfma_f32_16x16x32_bf16(a, b, acc[t], 0, 0, 0);
        }
    }

    // ---------------- epilogue: D layout col=lane&15, row=q*4+reg ----------------
    const float b0 = bias[0];
    const int row0 = oy0 + wv * 16 + q * 4;
#pragma unroll
    for (int t = 0; t < 4; ++t) {
        const int col = ox0 + t * 16 + m;
        if (col < OW) {
#pragma unroll
            for (int r = 0; r < 4; ++r) {
                const int row = row0 + r;
                if (row < OH)
                    out[(size_t)row * OW + col] = acc[t][r] + b0;
            }
        }
    }
}

extern "C" void kernel_launch(void* const* d_in, const int* in_sizes, int n_in,
                              void* d_out, int out_size, void* d_ws, size_t ws_size,
                              hipStream_t stream) {
    const float* x    = (const float*)d_in[0];
    const float* w    = (const float*)d_in[1];
    const float* bias = (const float*)d_in[2];
    float* out        = (float*)d_out;
    short* btab       = (short*)d_ws;   // 15*64*8 shorts = 15360 B

    conv2d_btab<<<dim3((KH * 64 + 255) / 256), dim3(256), 0, stream>>>(w, btab);

    dim3 grid((OW + BX - 1) / BX, (OH + BY - 1) / BY);  // 64 x 64
    dim3 block(256);
    conv2d_mfma<<<grid, block, 0, stream>>>(x, btab, bias, out);
}